// Round 20
// baseline (272.664 us; speedup 1.0000x reference)
//
#include <hip/hip_runtime.h>
#include <hip/hip_bf16.h>

namespace {
constexpr int kNA = 4353, kNM = 3676, kNT = 8000;
constexpr int kN  = kNA + kNM + kNT;      // 16029
constexpr int kE  = 500000;
constexpr int kS  = 200000;
constexpr int kDIN = 512, kDP = 256, kDE = 128, kDC = 64;

constexpr size_t OUT_X  = (size_t)kN * kDE;            // h first
constexpr size_t OUT_HM = OUT_X + 3ull * kS;           // then x, then h_movie

constexpr size_t align256(size_t x) { return (x + 255) & ~size_t(255); }

// ---- workspace layout (~23 MB peak) ----
constexpr size_t OFF_WPW1 = 0;                                    // 3 x 512 x 128 f32
constexpr size_t OFF_M9   = OFF_WPW1 + 3ull * 512 * 128 * 4;      // 9 x 128 x 16 f32
constexpr size_t OFF_HW1B = align256(OFF_M9 + 9ull * 2048 * 4);   // kN x 128 bf16
constexpr size_t OFF_H1B  = align256(OFF_HW1B + (size_t)kN * kDE * 2);
constexpr size_t OFF_AGG2 = align256(OFF_H1B + (size_t)kN * kDE * 2);  // kN x 128 f32
constexpr size_t OFF_P    = align256(OFF_AGG2 + (size_t)kN * kDE * 4); // 3 x kN x 16 f32
constexpr size_t OFF_ESRC = align256(OFF_P + 3ull * kN * 16 * 4);
constexpr size_t OFF_RP   = align256(OFF_ESRC + (size_t)kE * 4);
constexpr size_t OFF_CUR  = align256(OFF_RP + (size_t)(kN + 1) * 4);
constexpr size_t WS_NEEDED = align256(OFF_CUR + (size_t)kN * 4);

// hw1: 16 rows/block
constexpr int kBA = (kNA + 15) / 16;   // 273
constexpr int kBM = (kNM + 15) / 16;   // 230
constexpr int kBT = (kNT + 15) / 16;   // 500
constexpr int kHW1Blocks = kBA + kBM + kBT;          // 1003
constexpr int kG2Blocks  = (kN + 15) / 16;           // 1002
} // namespace

__device__ __forceinline__ float blo(unsigned u) { return __uint_as_float(u << 16); }
__device__ __forceinline__ float bhi(unsigned u) { return __uint_as_float(u & 0xffff0000u); }
__device__ __forceinline__ unsigned short b16(float f) {
    __hip_bfloat16 h = __float2bfloat16(f);
    return *reinterpret_cast<unsigned short*>(&h);
}
__device__ __forceinline__ unsigned pack2(float a, float b) {
    return (unsigned)b16(a) | ((unsigned)b16(b) << 16);
}

// ---- prep (fused): blocks 0..383 -> WpW1; 384..392 -> M9 ----
__global__ __launch_bounds__(128) void prep_kernel(
    const float* __restrict__ WpA, const float* __restrict__ WpM,
    const float* __restrict__ WpT, const float* __restrict__ W1,
    const float* __restrict__ WhA, const float* __restrict__ WhM,
    const float* __restrict__ WhT,
    const float* __restrict__ WcA, const float* __restrict__ WcM,
    const float* __restrict__ WcT,
    float* __restrict__ WpW1, float* __restrict__ M9)
{
    int b = blockIdx.x;
    if (b < 384) {
        int t = b >> 7;
        int k0 = (b & 127) * 4;
        const float* Wp = (t == 0) ? WpA : ((t == 1) ? WpM : WpT);
        int c = threadIdx.x;
        float acc[4] = {0.f, 0.f, 0.f, 0.f};
        for (int j = 0; j < kDP; j++) {
            float w1 = W1[j * kDE + c];
#pragma unroll
            for (int r = 0; r < 4; r++)
                acc[r] += Wp[(k0 + r) * kDP + j] * w1;   // uniform -> s_load
        }
#pragma unroll
        for (int r = 0; r < 4; r++)
            WpW1[((size_t)t * kDIN + k0 + r) * kDE + c] = acc[r];
    } else {
        int b2 = b - 384;                 // 0..8
        int g = b2 / 3, t = b2 % 3;
        const float* Wh = (g == 0) ? WhA : ((g == 1) ? WhM : WhT);
        const float* Wc = (t == 0) ? WcA : ((t == 1) ? WcM : WcT);
        int slot;
        if (t == g) slot = 0;
        else {
            int lower = (g == 0) ? 1 : 0;
            slot = (t == lower) ? 128 : 192;
        }
        float* Mout = M9 + (size_t)b2 * 2048;
        for (int idx = threadIdx.x; idx < 2048; idx += 128) {
            int k = idx >> 4, j = idx & 15;
            float v;
            if (slot == 0) v = Wh[k * 16 + j];
            else {
                v = 0.f;
                for (int d = 0; d < kDC; d++)
                    v += Wc[k * kDC + d] * Wh[(slot + d) * 16 + j];
            }
            Mout[idx] = v;
        }
    }
}

// ---- hw1: A tile (16x512) in LDS; thread = 4 rows x 2 cols;
//      rg = wave id -> LDS reads are full-wave broadcasts (conflict-free);
//      cp = lane -> float2 W loads, 512B/wave coalesced; bf16 packed store ----
__global__ __launch_bounds__(256) void hw1_kernel(
    const float* __restrict__ hA, const float* __restrict__ hM,
    const float* __restrict__ hT, const float* __restrict__ WpW1,
    __hip_bfloat16* __restrict__ HW1b)
{
    __shared__ float AL[16 * kDIN];           // 32 KB
    int b = blockIdx.x;
    const float *A, *W; int typeN, rowBase, lb;
    if (b < kBA)             { lb = b;             A = hA; W = WpW1;                   typeN = kNA; rowBase = 0; }
    else if (b < kBA + kBM)  { lb = b - kBA;       A = hM; W = WpW1 + 1ull*kDIN*kDE;   typeN = kNM; rowBase = kNA; }
    else                     { lb = b - kBA - kBM; A = hT; W = WpW1 + 2ull*kDIN*kDE;   typeN = kNT; rowBase = kNA + kNM; }
    int r0 = lb * 16;

    const float4* Ag = (const float4*)A;      // row stride 128 float4
#pragma unroll
    for (int i = 0; i < 8; i++) {
        int f = threadIdx.x + i * 256;        // 0..2047
        int rl = f >> 7, k4 = f & 127;
        int gr = min(r0 + rl, typeN - 1);
        ((float4*)AL)[f] = Ag[(size_t)gr * 128 + k4];
    }
    __syncthreads();                          // single barrier

    int rg = threadIdx.x >> 6;                // wave id: rows 4rg..4rg+3
    int cp = threadIdx.x & 63;                // cols 2cp, 2cp+1
    const float* ALh = AL + rg * 4 * kDIN;
    float2 acc[4];
#pragma unroll
    for (int r = 0; r < 4; r++) acc[r] = make_float2(0.f, 0.f);

    for (int k0 = 0; k0 < kDIN; k0 += 8) {
        float2 w[8];
#pragma unroll
        for (int i = 0; i < 8; i++)
            w[i] = *(const float2*)(W + (size_t)(k0 + i) * kDE + 2 * cp);  // coalesced
#pragma unroll
        for (int r = 0; r < 4; r++) {
            const float4 a0 = *(const float4*)(ALh + r * kDIN + k0);       // wave broadcast
            const float4 a1 = *(const float4*)(ALh + r * kDIN + k0 + 4);
            acc[r].x += a0.x * w[0].x + a0.y * w[1].x + a0.z * w[2].x + a0.w * w[3].x
                      + a1.x * w[4].x + a1.y * w[5].x + a1.z * w[6].x + a1.w * w[7].x;
            acc[r].y += a0.x * w[0].y + a0.y * w[1].y + a0.z * w[2].y + a0.w * w[3].y
                      + a1.x * w[4].y + a1.y * w[5].y + a1.z * w[6].y + a1.w * w[7].y;
        }
    }
#pragma unroll
    for (int r = 0; r < 4; r++) {
        int lr = r0 + rg * 4 + r;
        if (lr < typeN) {
            unsigned o = pack2(acc[r].x, acc[r].y);
            *((unsigned*)(HW1b + (size_t)(rowBase + lr) * kDE) + cp) = o;  // 4B/lane coalesced
        }
    }
}

// ---- CSR build (clamped) ----
__device__ __forceinline__ int clampN(int v) { return min(max(v, 0), kN - 1); }

__global__ __launch_bounds__(256) void hist_kernel(const int* __restrict__ key,
                                                   int* __restrict__ counts)
{
    int e = blockIdx.x * 256 + threadIdx.x;
    if (e < kE) atomicAdd(&counts[clampN(key[e])], 1);
}

__global__ __launch_bounds__(256) void scan_kernel(int* __restrict__ cnt_cur,
                                                   int* __restrict__ rowptr)
{
    __shared__ int sums[256];
    int tid = threadIdx.x;
    int i0 = tid * 63, i1 = min(i0 + 63, kN);
    int s = 0;
    for (int i = i0; i < i1; i++) s += cnt_cur[i];
    sums[tid] = s;
    __syncthreads();
    if (tid == 0) {
        int run = 0;
        for (int i = 0; i < 256; i++) { int v = sums[i]; sums[i] = run; run += v; }
    }
    __syncthreads();
    int base = sums[tid];
    for (int i = i0; i < i1; i++) {
        int c = cnt_cur[i];
        rowptr[i] = base;
        cnt_cur[i] = base;       // becomes fill cursor
        base += c;
    }
    if (tid == 0) rowptr[kN] = kE;
}

__global__ __launch_bounds__(256) void fill_kernel(const int* __restrict__ stored,
                                                   const int* __restrict__ key,
                                                   int* __restrict__ cursor,
                                                   int* __restrict__ esrc)
{
    int e = blockIdx.x * 256 + threadIdx.x;
    if (e < kE) {
        int p = atomicAdd(&cursor[clampN(key[e])], 1);
        esrc[min(p, kE - 1)] = clampN(stored[e]);
    }
}

// ---- aggv over bf16 rows: out[n] = sum X[esrc[e]]; FIRST: +b1,relu, bf16 out ----
template <bool FIRST>
__global__ __launch_bounds__(64) void aggv_kernel(const __hip_bfloat16* __restrict__ Xb,
                                                  const int* __restrict__ rowptr,
                                                  const int* __restrict__ esrc,
                                                  const float* __restrict__ b1,
                                                  void* __restrict__ outv)
{
    int n = blockIdx.x;
    int lane = threadIdx.x;           // 0..63
    int eo = lane >> 5;               // 0/1: even/odd edges
    int cg = lane & 31;               // uint2 group: bf16 cols 4cg..4cg+3
    int start = rowptr[n], end = rowptr[n + 1];
    const uint2* X2 = (const uint2*)Xb;       // row stride 32 uint2
    float4 a0 = {0.f, 0.f, 0.f, 0.f}, a1 = {0.f, 0.f, 0.f, 0.f};
    int j = start + eo;
    for (; j + 2 < end; j += 4) {
        uint2 v0 = X2[(size_t)esrc[j] * 32 + cg];
        uint2 v1 = X2[(size_t)esrc[j + 2] * 32 + cg];
        a0.x += blo(v0.x); a0.y += bhi(v0.x); a0.z += blo(v0.y); a0.w += bhi(v0.y);
        a1.x += blo(v1.x); a1.y += bhi(v1.x); a1.z += blo(v1.y); a1.w += bhi(v1.y);
    }
    if (j < end) {
        uint2 v0 = X2[(size_t)esrc[j] * 32 + cg];
        a0.x += blo(v0.x); a0.y += bhi(v0.x); a0.z += blo(v0.y); a0.w += bhi(v0.y);
    }
    float4 acc;
    acc.x = a0.x + a1.x; acc.y = a0.y + a1.y;
    acc.z = a0.z + a1.z; acc.w = a0.w + a1.w;
    acc.x += __shfl_xor(acc.x, 32);           // combine eo halves in-wave
    acc.y += __shfl_xor(acc.y, 32);
    acc.z += __shfl_xor(acc.z, 32);
    acc.w += __shfl_xor(acc.w, 32);
    if (lane < 32) {
        if (FIRST) {
            const float4 bv = ((const float4*)b1)[cg];
            acc.x = fmaxf(acc.x + bv.x, 0.f);
            acc.y = fmaxf(acc.y + bv.y, 0.f);
            acc.z = fmaxf(acc.z + bv.z, 0.f);
            acc.w = fmaxf(acc.w + bv.w, 0.f);
            uint2 o;
            o.x = pack2(acc.x, acc.y);
            o.y = pack2(acc.z, acc.w);
            ((uint2*)outv)[(size_t)n * 32 + cg] = o;
        } else {
            ((float4*)outv)[(size_t)n * 32 + cg] = acc;
        }
    }
}

// ---- gemm2 + norm + partial fused ----
__global__ __launch_bounds__(256) void gemm2_norm_p_kernel(
    const float* __restrict__ X, const float* __restrict__ W2,
    const float* __restrict__ b2, const float* __restrict__ M9,
    float* __restrict__ P, float* __restrict__ out)
{
    __shared__ float AL[16 * kDE];            // 8 KB: gemm A-tile, then hn tile
    __shared__ float red[16][2];
    int r0 = blockIdx.x * 16;

    const float4* Xg = (const float4*)X;      // row stride 32 float4
#pragma unroll
    for (int i = 0; i < 2; i++) {
        int f = threadIdx.x + i * 256;        // 0..511
        int rl = f >> 5, k4 = f & 31;
        int gr = min(r0 + rl, kN - 1);
        ((float4*)AL)[f] = Xg[(size_t)gr * 32 + k4];
    }
    __syncthreads();

    int col = threadIdx.x & 127;
    int hh  = threadIdx.x >> 7;
    const float* ALh = AL + hh * 8 * kDE;
    float acc[8];
#pragma unroll
    for (int r = 0; r < 8; r++) acc[r] = 0.f;

    for (int k0 = 0; k0 < kDE; k0 += 8) {
        float w[8];
#pragma unroll
        for (int i = 0; i < 8; i++)
            w[i] = W2[(size_t)(k0 + i) * kDE + col];
#pragma unroll
        for (int r = 0; r < 8; r++) {
            const float4 a0 = *(const float4*)(ALh + r * kDE + k0);
            const float4 a1 = *(const float4*)(ALh + r * kDE + k0 + 4);
            acc[r] += a0.x * w[0] + a0.y * w[1] + a0.z * w[2] + a0.w * w[3]
                    + a1.x * w[4] + a1.y * w[5] + a1.z * w[6] + a1.w * w[7];
        }
    }

    float bv = b2[col];
    int half = (threadIdx.x >> 6) & 1;
#pragma unroll
    for (int r = 0; r < 8; r++) {
        float v = acc[r] + bv;
        acc[r] = v;
        float ss = v * v;
#pragma unroll
        for (int o = 32; o > 0; o >>= 1) ss += __shfl_xor(ss, o);
        if ((threadIdx.x & 63) == 0) red[hh * 8 + r][half] = ss;
    }
    __syncthreads();                          // all k-loop reads of AL are done
#pragma unroll
    for (int r = 0; r < 8; r++) {
        int lrow = hh * 8 + r;
        int gr = r0 + lrow;
        if (gr < kN) {
            float tot = red[lrow][0] + red[lrow][1];
            float sc = 1.f / fmaxf(sqrtf(tot), 1e-12f);
            float hv = acc[r] * sc;
            AL[lrow * kDE + col] = hv;        // hn tile for P phase
            out[(size_t)gr * kDE + col] = hv;
            if (gr >= kNA && gr < kNA + kNM)
                out[OUT_HM + (size_t)(gr - kNA) * kDE + col] = hv;
        }
    }
    __syncthreads();

    // P phase: thread (r, j) computes P[g][r0+r][j] for g = 0..2
    int r = threadIdx.x >> 4, j = threadIdx.x & 15;
    int gr = r0 + r;
    if (gr >= kN) return;
    int t = (gr < kNA) ? 0 : ((gr < kNA + kNM) ? 1 : 2);
    const float* Hr = AL + r * kDE;
#pragma unroll
    for (int g = 0; g < 3; g++) {
        const float* M = M9 + (size_t)(g * 3 + t) * 2048;
        float acc2 = 0.f;
        for (int k = 0; k < kDE; k += 4) {
            const float4 h4 = *(const float4*)(Hr + k);
            acc2 += h4.x * M[(k + 0) * 16 + j] + h4.y * M[(k + 1) * 16 + j]
                  + h4.z * M[(k + 2) * 16 + j] + h4.w * M[(k + 3) * 16 + j];
        }
        P[((size_t)g * kN + gr) * 16 + j] = acc2;
    }
}

// ---- classifier-lite: 3 x 16-float gathers + relu-dot + sigmoid ----
__global__ __launch_bounds__(256) void cls_lite_kernel(
    const float* __restrict__ P,
    const int* __restrict__ n0a, const int* __restrict__ n0m, const int* __restrict__ n0t,
    const int* __restrict__ n1a, const int* __restrict__ n1m, const int* __restrict__ n1t,
    const int* __restrict__ n2a, const int* __restrict__ n2m, const int* __restrict__ n2t,
    const float* __restrict__ WoA, const float* __restrict__ WoM, const float* __restrict__ WoT,
    float* __restrict__ out, int blocksPerGroup)
{
    int g = blockIdx.x / blocksPerGroup;
    int i = (blockIdx.x % blocksPerGroup) * 256 + threadIdx.x;
    if (i >= kS) return;
    auto cA = [](int v){ return min(max(v, 0), kNA - 1); };
    auto cM = [](int v){ return min(max(v, 0), kNM - 1); };
    auto cT = [](int v){ return min(max(v, 0), kNT - 1); };
    int ra, rb, rc;
    if (g == 0)      { ra = cA(n0a[i]);             rb = kNA + cM(n0m[i]);  rc = kNA + kNM + cT(n0t[i]); }
    else if (g == 1) { ra = kNA + cM(n1m[i]);       rb = cA(n1a[i]);        rc = kNA + kNM + cT(n1t[i]); }
    else             { ra = kNA + kNM + cT(n2t[i]); rb = cA(n2a[i]);        rc = kNA + cM(n2m[i]); }
    const float* Pg = P + (size_t)g * kN * 16;
    const float* wo = (g == 0) ? WoA : ((g == 1) ? WoM : WoT);   // uniform -> s_load
    const float4* pa = (const float4*)(Pg + (size_t)ra * 16);
    const float4* pb = (const float4*)(Pg + (size_t)rb * 16);
    const float4* pc = (const float4*)(Pg + (size_t)rc * 16);
    float p = 0.f;
#pragma unroll
    for (int q = 0; q < 4; q++) {
        float4 a = pa[q], b = pb[q], c = pc[q];
        p += fmaxf(a.x + b.x + c.x, 0.f) * wo[q * 4 + 0];
        p += fmaxf(a.y + b.y + c.y, 0.f) * wo[q * 4 + 1];
        p += fmaxf(a.z + b.z + c.z, 0.f) * wo[q * 4 + 2];
        p += fmaxf(a.w + b.w + c.w, 0.f) * wo[q * 4 + 3];
    }
    out[OUT_X + (size_t)g * kS + i] = 1.f / (1.f + expf(-p));
}

extern "C" void kernel_launch(void* const* d_in, const int* in_sizes, int n_in,
                              void* d_out, int out_size, void* d_ws, size_t ws_size,
                              hipStream_t stream)
{
    (void)out_size;
    static const int expected[30] = {
        2228736, 1882112, 4096000, 131072, 131072, 131072, 32768, 128, 16384, 128,
        8192, 8192, 8192, 4096, 4096, 4096, 16, 16, 16,
        500000, 500000, 200000, 200000, 200000, 200000, 200000, 200000, 200000, 200000, 200000 };
    if (n_in != 30) return;
    for (int i = 0; i < 30; i++) if (in_sizes[i] != expected[i]) return;
    if (ws_size < WS_NEEDED) return;

    // inputs proven f32 / int32 (rounds 7-10)
    const float* h_a  = (const float*)d_in[0];
    const float* h_m  = (const float*)d_in[1];
    const float* h_t  = (const float*)d_in[2];
    const float* Wp_a = (const float*)d_in[3];
    const float* Wp_m = (const float*)d_in[4];
    const float* Wp_t = (const float*)d_in[5];
    const float* W1   = (const float*)d_in[6];
    const float* b1   = (const float*)d_in[7];
    const float* W2   = (const float*)d_in[8];
    const float* b2   = (const float*)d_in[9];
    const float* Wc_a = (const float*)d_in[10];
    const float* Wc_m = (const float*)d_in[11];
    const float* Wc_t = (const float*)d_in[12];
    const float* Wh_a = (const float*)d_in[13];
    const float* Wh_m = (const float*)d_in[14];
    const float* Wh_t = (const float*)d_in[15];
    const float* Wo_a = (const float*)d_in[16];
    const float* Wo_m = (const float*)d_in[17];
    const float* Wo_t = (const float*)d_in[18];
    const int* src = (const int*)d_in[19];
    const int* dst = (const int*)d_in[20];

    char* ws = (char*)d_ws;
    float* WpW1 = (float*)(ws + OFF_WPW1);
    float* M9   = (float*)(ws + OFF_M9);
    __hip_bfloat16* HW1b = (__hip_bfloat16*)(ws + OFF_HW1B);
    __hip_bfloat16* h1b  = (__hip_bfloat16*)(ws + OFF_H1B);
    float* agg2 = (float*)(ws + OFF_AGG2);
    float* P    = (float*)(ws + OFF_P);
    int* esrc   = (int*)(ws + OFF_ESRC);
    int* rowptr = (int*)(ws + OFF_RP);
    int* cursor = (int*)(ws + OFF_CUR);
    float* out  = (float*)d_out;

    hipMemsetAsync(cursor, 0, (size_t)kN * 4, stream);

    hist_kernel<<<dim3(1954), dim3(256), 0, stream>>>(dst, cursor);
    scan_kernel<<<dim3(1), dim3(256), 0, stream>>>(cursor, rowptr);
    fill_kernel<<<dim3(1954), dim3(256), 0, stream>>>(src, dst, cursor, esrc);

    prep_kernel<<<dim3(393), dim3(128), 0, stream>>>(Wp_a, Wp_m, Wp_t, W1,
        Wh_a, Wh_m, Wh_t, Wc_a, Wc_m, Wc_t, WpW1, M9);

    hw1_kernel<<<dim3(kHW1Blocks), dim3(256), 0, stream>>>(h_a, h_m, h_t, WpW1, HW1b);
    aggv_kernel<true><<<dim3(kN), dim3(64), 0, stream>>>(HW1b, rowptr, esrc, b1, h1b);
    aggv_kernel<false><<<dim3(kN), dim3(64), 0, stream>>>(h1b, rowptr, esrc, b1, agg2);
    gemm2_norm_p_kernel<<<dim3(kG2Blocks), dim3(256), 0, stream>>>(agg2, W2, b2, M9, P, out);
    cls_lite_kernel<<<dim3(2346), dim3(256), 0, stream>>>(P,
        (const int*)d_in[21], (const int*)d_in[22], (const int*)d_in[23],
        (const int*)d_in[24], (const int*)d_in[25], (const int*)d_in[26],
        (const int*)d_in[27], (const int*)d_in[28], (const int*)d_in[29],
        Wo_a, Wo_m, Wo_t, out, 782);
}

// Round 21
// 259.919 us; speedup vs baseline: 1.0490x; 1.0490x over previous
//
#include <hip/hip_runtime.h>
#include <hip/hip_bf16.h>

namespace {
constexpr int kNA = 4353, kNM = 3676, kNT = 8000;
constexpr int kN  = kNA + kNM + kNT;      // 16029
constexpr int kE  = 500000;
constexpr int kS  = 200000;
constexpr int kDIN = 512, kDP = 256, kDE = 128, kDC = 64;

constexpr size_t OUT_X  = (size_t)kN * kDE;            // h first
constexpr size_t OUT_HM = OUT_X + 3ull * kS;           // then x, then h_movie

constexpr size_t align256(size_t x) { return (x + 255) & ~size_t(255); }

// ---- workspace layout (~23 MB peak) ----
constexpr size_t OFF_WPW1 = 0;                                    // 3 x 512 x 128 f32
constexpr size_t OFF_M9   = OFF_WPW1 + 3ull * 512 * 128 * 4;      // 9 x 128 x 16 f32
constexpr size_t OFF_HW1B = align256(OFF_M9 + 9ull * 2048 * 4);   // kN x 128 bf16
constexpr size_t OFF_H1B  = align256(OFF_HW1B + (size_t)kN * kDE * 2);
constexpr size_t OFF_AGG2 = align256(OFF_H1B + (size_t)kN * kDE * 2);  // kN x 128 f32
constexpr size_t OFF_P    = align256(OFF_AGG2 + (size_t)kN * kDE * 4); // 3 x kN x 16 f32
constexpr size_t OFF_ESRC = align256(OFF_P + 3ull * kN * 16 * 4);
constexpr size_t OFF_RP   = align256(OFF_ESRC + (size_t)kE * 4);
constexpr size_t OFF_CUR  = align256(OFF_RP + (size_t)(kN + 1) * 4);
constexpr size_t WS_NEEDED = align256(OFF_CUR + (size_t)kN * 4);

// hw1: 16 rows/block (r14/r19 proven config)
constexpr int kBA = (kNA + 15) / 16;   // 273
constexpr int kBM = (kNM + 15) / 16;   // 230
constexpr int kBT = (kNT + 15) / 16;   // 500
constexpr int kHW1Blocks = kBA + kBM + kBT;          // 1003
constexpr int kG2Blocks  = (kN + 15) / 16;           // 1002
} // namespace

__device__ __forceinline__ float blo(unsigned u) { return __uint_as_float(u << 16); }
__device__ __forceinline__ float bhi(unsigned u) { return __uint_as_float(u & 0xffff0000u); }
__device__ __forceinline__ unsigned short b16(float f) {
    __hip_bfloat16 h = __float2bfloat16(f);
    return *reinterpret_cast<unsigned short*>(&h);
}
__device__ __forceinline__ unsigned pack2(float a, float b) {
    return (unsigned)b16(a) | ((unsigned)b16(b) << 16);
}

// ---- prep (fused): blocks 0..383 -> WpW1; 384..392 -> M9 ----
__global__ __launch_bounds__(128) void prep_kernel(
    const float* __restrict__ WpA, const float* __restrict__ WpM,
    const float* __restrict__ WpT, const float* __restrict__ W1,
    const float* __restrict__ WhA, const float* __restrict__ WhM,
    const float* __restrict__ WhT,
    const float* __restrict__ WcA, const float* __restrict__ WcM,
    const float* __restrict__ WcT,
    float* __restrict__ WpW1, float* __restrict__ M9)
{
    int b = blockIdx.x;
    if (b < 384) {
        int t = b >> 7;
        int k0 = (b & 127) * 4;
        const float* Wp = (t == 0) ? WpA : ((t == 1) ? WpM : WpT);
        int c = threadIdx.x;
        float acc[4] = {0.f, 0.f, 0.f, 0.f};
        for (int j = 0; j < kDP; j++) {
            float w1 = W1[j * kDE + c];
#pragma unroll
            for (int r = 0; r < 4; r++)
                acc[r] += Wp[(k0 + r) * kDP + j] * w1;   // uniform -> s_load
        }
#pragma unroll
        for (int r = 0; r < 4; r++)
            WpW1[((size_t)t * kDIN + k0 + r) * kDE + c] = acc[r];
    } else {
        int b2 = b - 384;                 // 0..8
        int g = b2 / 3, t = b2 % 3;
        const float* Wh = (g == 0) ? WhA : ((g == 1) ? WhM : WhT);
        const float* Wc = (t == 0) ? WcA : ((t == 1) ? WcM : WcT);
        int slot;
        if (t == g) slot = 0;
        else {
            int lower = (g == 0) ? 1 : 0;
            slot = (t == lower) ? 128 : 192;
        }
        float* Mout = M9 + (size_t)b2 * 2048;
        for (int idx = threadIdx.x; idx < 2048; idx += 128) {
            int k = idx >> 4, j = idx & 15;
            float v;
            if (slot == 0) v = Wh[k * 16 + j];
            else {
                v = 0.f;
                for (int d = 0; d < kDC; d++)
                    v += Wc[k * kDC + d] * Wh[(slot + d) * 16 + j];
            }
            Mout[idx] = v;
        }
    }
}

// ---- hw1 (r19 proven): A tile in LDS; W streamed scalar; OUTPUT bf16 ----
__global__ __launch_bounds__(256) void hw1_kernel(
    const float* __restrict__ hA, const float* __restrict__ hM,
    const float* __restrict__ hT, const float* __restrict__ WpW1,
    __hip_bfloat16* __restrict__ HW1b)
{
    __shared__ float AL[16 * kDIN];           // 32 KB
    int b = blockIdx.x;
    const float *A, *W; int typeN, rowBase, lb;
    if (b < kBA)             { lb = b;             A = hA; W = WpW1;                   typeN = kNA; rowBase = 0; }
    else if (b < kBA + kBM)  { lb = b - kBA;       A = hM; W = WpW1 + 1ull*kDIN*kDE;   typeN = kNM; rowBase = kNA; }
    else                     { lb = b - kBA - kBM; A = hT; W = WpW1 + 2ull*kDIN*kDE;   typeN = kNT; rowBase = kNA + kNM; }
    int r0 = lb * 16;

    const float4* Ag = (const float4*)A;      // row stride 128 float4
#pragma unroll
    for (int i = 0; i < 8; i++) {
        int f = threadIdx.x + i * 256;        // 0..2047
        int rl = f >> 7, k4 = f & 127;
        int gr = min(r0 + rl, typeN - 1);
        ((float4*)AL)[f] = Ag[(size_t)gr * 128 + k4];
    }
    __syncthreads();                          // single barrier

    int col = threadIdx.x & 127;
    int hh  = threadIdx.x >> 7;               // 0/1 -> rows 0..7 / 8..15
    const float* ALh = AL + hh * 8 * kDIN;
    float acc[8];
#pragma unroll
    for (int r = 0; r < 8; r++) acc[r] = 0.f;

    for (int k0 = 0; k0 < kDIN; k0 += 8) {
        float w[8];
#pragma unroll
        for (int i = 0; i < 8; i++)
            w[i] = W[(size_t)(k0 + i) * kDE + col];   // per-lane coalesced, L2-hot
#pragma unroll
        for (int r = 0; r < 8; r++) {
            const float4 a0 = *(const float4*)(ALh + r * kDIN + k0);       // LDS broadcast
            const float4 a1 = *(const float4*)(ALh + r * kDIN + k0 + 4);
            acc[r] += a0.x * w[0] + a0.y * w[1] + a0.z * w[2] + a0.w * w[3]
                    + a1.x * w[4] + a1.y * w[5] + a1.z * w[6] + a1.w * w[7];
        }
    }
#pragma unroll
    for (int r = 0; r < 8; r++) {
        int lr = r0 + hh * 8 + r;
        if (lr < typeN) HW1b[(size_t)(rowBase + lr) * kDE + col] = __float2bfloat16(acc[r]);
    }
}

// ---- CSR build (clamped) ----
__device__ __forceinline__ int clampN(int v) { return min(max(v, 0), kN - 1); }

__global__ __launch_bounds__(256) void hist_kernel(const int* __restrict__ key,
                                                   int* __restrict__ counts)
{
    int e = blockIdx.x * 256 + threadIdx.x;
    if (e < kE) atomicAdd(&counts[clampN(key[e])], 1);
}

__global__ __launch_bounds__(256) void scan_kernel(int* __restrict__ cnt_cur,
                                                   int* __restrict__ rowptr)
{
    __shared__ int sums[256];
    int tid = threadIdx.x;
    int i0 = tid * 63, i1 = min(i0 + 63, kN);
    int s = 0;
    for (int i = i0; i < i1; i++) s += cnt_cur[i];
    sums[tid] = s;
    __syncthreads();
    if (tid == 0) {
        int run = 0;
        for (int i = 0; i < 256; i++) { int v = sums[i]; sums[i] = run; run += v; }
    }
    __syncthreads();
    int base = sums[tid];
    for (int i = i0; i < i1; i++) {
        int c = cnt_cur[i];
        rowptr[i] = base;
        cnt_cur[i] = base;       // becomes fill cursor
        base += c;
    }
    if (tid == 0) rowptr[kN] = kE;
}

__global__ __launch_bounds__(256) void fill_kernel(const int* __restrict__ stored,
                                                   const int* __restrict__ key,
                                                   int* __restrict__ cursor,
                                                   int* __restrict__ esrc)
{
    int e = blockIdx.x * 256 + threadIdx.x;
    if (e < kE) {
        int p = atomicAdd(&cursor[clampN(key[e])], 1);
        esrc[min(p, kE - 1)] = clampN(stored[e]);
    }
}

// ---- aggv over bf16 rows, 4 gathers in flight per eo-half ----
template <bool FIRST>
__global__ __launch_bounds__(64) void aggv_kernel(const __hip_bfloat16* __restrict__ Xb,
                                                  const int* __restrict__ rowptr,
                                                  const int* __restrict__ esrc,
                                                  const float* __restrict__ b1,
                                                  void* __restrict__ outv)
{
    int n = blockIdx.x;
    int lane = threadIdx.x;           // 0..63
    int eo = lane >> 5;               // 0/1: even/odd edges
    int cg = lane & 31;               // uint2 group: bf16 cols 4cg..4cg+3
    int start = rowptr[n], end = rowptr[n + 1];
    const uint2* X2 = (const uint2*)Xb;       // row stride 32 uint2
    float4 a0 = {0.f, 0.f, 0.f, 0.f}, a1 = {0.f, 0.f, 0.f, 0.f};
    float4 a2 = {0.f, 0.f, 0.f, 0.f}, a3 = {0.f, 0.f, 0.f, 0.f};
    int j = start + eo;
    for (; j + 6 < end; j += 8) {             // 4 gathers in flight / half
        uint2 v0 = X2[(size_t)esrc[j] * 32 + cg];
        uint2 v1 = X2[(size_t)esrc[j + 2] * 32 + cg];
        uint2 v2 = X2[(size_t)esrc[j + 4] * 32 + cg];
        uint2 v3 = X2[(size_t)esrc[j + 6] * 32 + cg];
        a0.x += blo(v0.x); a0.y += bhi(v0.x); a0.z += blo(v0.y); a0.w += bhi(v0.y);
        a1.x += blo(v1.x); a1.y += bhi(v1.x); a1.z += blo(v1.y); a1.w += bhi(v1.y);
        a2.x += blo(v2.x); a2.y += bhi(v2.x); a2.z += blo(v2.y); a2.w += bhi(v2.y);
        a3.x += blo(v3.x); a3.y += bhi(v3.x); a3.z += blo(v3.y); a3.w += bhi(v3.y);
    }
    for (; j < end; j += 2) {
        uint2 v0 = X2[(size_t)esrc[j] * 32 + cg];
        a0.x += blo(v0.x); a0.y += bhi(v0.x); a0.z += blo(v0.y); a0.w += bhi(v0.y);
    }
    float4 acc;
    acc.x = (a0.x + a1.x) + (a2.x + a3.x);
    acc.y = (a0.y + a1.y) + (a2.y + a3.y);
    acc.z = (a0.z + a1.z) + (a2.z + a3.z);
    acc.w = (a0.w + a1.w) + (a2.w + a3.w);
    acc.x += __shfl_xor(acc.x, 32);           // combine eo halves in-wave
    acc.y += __shfl_xor(acc.y, 32);
    acc.z += __shfl_xor(acc.z, 32);
    acc.w += __shfl_xor(acc.w, 32);
    if (lane < 32) {
        if (FIRST) {
            const float4 bv = ((const float4*)b1)[cg];
            acc.x = fmaxf(acc.x + bv.x, 0.f);
            acc.y = fmaxf(acc.y + bv.y, 0.f);
            acc.z = fmaxf(acc.z + bv.z, 0.f);
            acc.w = fmaxf(acc.w + bv.w, 0.f);
            uint2 o;
            o.x = pack2(acc.x, acc.y);
            o.y = pack2(acc.z, acc.w);
            ((uint2*)outv)[(size_t)n * 32 + cg] = o;
        } else {
            ((float4*)outv)[(size_t)n * 32 + cg] = acc;
        }
    }
}

// ---- gemm2 + norm + partial fused ----
__global__ __launch_bounds__(256) void gemm2_norm_p_kernel(
    const float* __restrict__ X, const float* __restrict__ W2,
    const float* __restrict__ b2, const float* __restrict__ M9,
    float* __restrict__ P, float* __restrict__ out)
{
    __shared__ float AL[16 * kDE];            // 8 KB: gemm A-tile, then hn tile
    __shared__ float red[16][2];
    int r0 = blockIdx.x * 16;

    const float4* Xg = (const float4*)X;      // row stride 32 float4
#pragma unroll
    for (int i = 0; i < 2; i++) {
        int f = threadIdx.x + i * 256;        // 0..511
        int rl = f >> 5, k4 = f & 31;
        int gr = min(r0 + rl, kN - 1);
        ((float4*)AL)[f] = Xg[(size_t)gr * 32 + k4];
    }
    __syncthreads();

    int col = threadIdx.x & 127;
    int hh  = threadIdx.x >> 7;
    const float* ALh = AL + hh * 8 * kDE;
    float acc[8];
#pragma unroll
    for (int r = 0; r < 8; r++) acc[r] = 0.f;

    for (int k0 = 0; k0 < kDE; k0 += 8) {
        float w[8];
#pragma unroll
        for (int i = 0; i < 8; i++)
            w[i] = W2[(size_t)(k0 + i) * kDE + col];
#pragma unroll
        for (int r = 0; r < 8; r++) {
            const float4 a0 = *(const float4*)(ALh + r * kDE + k0);
            const float4 a1 = *(const float4*)(ALh + r * kDE + k0 + 4);
            acc[r] += a0.x * w[0] + a0.y * w[1] + a0.z * w[2] + a0.w * w[3]
                    + a1.x * w[4] + a1.y * w[5] + a1.z * w[6] + a1.w * w[7];
        }
    }

    float bv = b2[col];
    int half = (threadIdx.x >> 6) & 1;
#pragma unroll
    for (int r = 0; r < 8; r++) {
        float v = acc[r] + bv;
        acc[r] = v;
        float ss = v * v;
#pragma unroll
        for (int o = 32; o > 0; o >>= 1) ss += __shfl_xor(ss, o);
        if ((threadIdx.x & 63) == 0) red[hh * 8 + r][half] = ss;
    }
    __syncthreads();                          // all k-loop reads of AL are done
#pragma unroll
    for (int r = 0; r < 8; r++) {
        int lrow = hh * 8 + r;
        int gr = r0 + lrow;
        if (gr < kN) {
            float tot = red[lrow][0] + red[lrow][1];
            float sc = 1.f / fmaxf(sqrtf(tot), 1e-12f);
            float hv = acc[r] * sc;
            AL[lrow * kDE + col] = hv;        // hn tile for P phase
            out[(size_t)gr * kDE + col] = hv;
            if (gr >= kNA && gr < kNA + kNM)
                out[OUT_HM + (size_t)(gr - kNA) * kDE + col] = hv;
        }
    }
    __syncthreads();

    // P phase: thread (r, j) computes P[g][r0+r][j] for g = 0..2
    int r = threadIdx.x >> 4, j = threadIdx.x & 15;
    int gr = r0 + r;
    if (gr >= kN) return;
    int t = (gr < kNA) ? 0 : ((gr < kNA + kNM) ? 1 : 2);
    const float* Hr = AL + r * kDE;
#pragma unroll
    for (int g = 0; g < 3; g++) {
        const float* M = M9 + (size_t)(g * 3 + t) * 2048;
        float acc2 = 0.f;
        for (int k = 0; k < kDE; k += 4) {
            const float4 h4 = *(const float4*)(Hr + k);
            acc2 += h4.x * M[(k + 0) * 16 + j] + h4.y * M[(k + 1) * 16 + j]
                  + h4.z * M[(k + 2) * 16 + j] + h4.w * M[(k + 3) * 16 + j];
        }
        P[((size_t)g * kN + gr) * 16 + j] = acc2;
    }
}

// ---- classifier-lite: 3 x 16-float gathers + relu-dot + sigmoid ----
__global__ __launch_bounds__(256) void cls_lite_kernel(
    const float* __restrict__ P,
    const int* __restrict__ n0a, const int* __restrict__ n0m, const int* __restrict__ n0t,
    const int* __restrict__ n1a, const int* __restrict__ n1m, const int* __restrict__ n1t,
    const int* __restrict__ n2a, const int* __restrict__ n2m, const int* __restrict__ n2t,
    const float* __restrict__ WoA, const float* __restrict__ WoM, const float* __restrict__ WoT,
    float* __restrict__ out, int blocksPerGroup)
{
    int g = blockIdx.x / blocksPerGroup;
    int i = (blockIdx.x % blocksPerGroup) * 256 + threadIdx.x;
    if (i >= kS) return;
    auto cA = [](int v){ return min(max(v, 0), kNA - 1); };
    auto cM = [](int v){ return min(max(v, 0), kNM - 1); };
    auto cT = [](int v){ return min(max(v, 0), kNT - 1); };
    int ra, rb, rc;
    if (g == 0)      { ra = cA(n0a[i]);             rb = kNA + cM(n0m[i]);  rc = kNA + kNM + cT(n0t[i]); }
    else if (g == 1) { ra = kNA + cM(n1m[i]);       rb = cA(n1a[i]);        rc = kNA + kNM + cT(n1t[i]); }
    else             { ra = kNA + kNM + cT(n2t[i]); rb = cA(n2a[i]);        rc = kNA + cM(n2m[i]); }
    const float* Pg = P + (size_t)g * kN * 16;
    const float* wo = (g == 0) ? WoA : ((g == 1) ? WoM : WoT);   // uniform -> s_load
    const float4* pa = (const float4*)(Pg + (size_t)ra * 16);
    const float4* pb = (const float4*)(Pg + (size_t)rb * 16);
    const float4* pc = (const float4*)(Pg + (size_t)rc * 16);
    float p = 0.f;
#pragma unroll
    for (int q = 0; q < 4; q++) {
        float4 a = pa[q], b = pb[q], c = pc[q];
        p += fmaxf(a.x + b.x + c.x, 0.f) * wo[q * 4 + 0];
        p += fmaxf(a.y + b.y + c.y, 0.f) * wo[q * 4 + 1];
        p += fmaxf(a.z + b.z + c.z, 0.f) * wo[q * 4 + 2];
        p += fmaxf(a.w + b.w + c.w, 0.f) * wo[q * 4 + 3];
    }
    out[OUT_X + (size_t)g * kS + i] = 1.f / (1.f + expf(-p));
}

extern "C" void kernel_launch(void* const* d_in, const int* in_sizes, int n_in,
                              void* d_out, int out_size, void* d_ws, size_t ws_size,
                              hipStream_t stream)
{
    (void)out_size;
    static const int expected[30] = {
        2228736, 1882112, 4096000, 131072, 131072, 131072, 32768, 128, 16384, 128,
        8192, 8192, 8192, 4096, 4096, 4096, 16, 16, 16,
        500000, 500000, 200000, 200000, 200000, 200000, 200000, 200000, 200000, 200000, 200000 };
    if (n_in != 30) return;
    for (int i = 0; i < 30; i++) if (in_sizes[i] != expected[i]) return;
    if (ws_size < WS_NEEDED) return;

    // inputs proven f32 / int32 (rounds 7-10)
    const float* h_a  = (const float*)d_in[0];
    const float* h_m  = (const float*)d_in[1];
    const float* h_t  = (const float*)d_in[2];
    const float* Wp_a = (const float*)d_in[3];
    const float* Wp_m = (const float*)d_in[4];
    const float* Wp_t = (const float*)d_in[5];
    const float* W1   = (const float*)d_in[6];
    const float* b1   = (const float*)d_in[7];
    const float* W2   = (const float*)d_in[8];
    const float* b2   = (const float*)d_in[9];
    const float* Wc_a = (const float*)d_in[10];
    const float* Wc_m = (const float*)d_in[11];
    const float* Wc_t = (const float*)d_in[12];
    const float* Wh_a = (const float*)d_in[13];
    const float* Wh_m = (const float*)d_in[14];
    const float* Wh_t = (const float*)d_in[15];
    const float* Wo_a = (const float*)d_in[16];
    const float* Wo_m = (const float*)d_in[17];
    const float* Wo_t = (const float*)d_in[18];
    const int* src = (const int*)d_in[19];
    const int* dst = (const int*)d_in[20];

    char* ws = (char*)d_ws;
    float* WpW1 = (float*)(ws + OFF_WPW1);
    float* M9   = (float*)(ws + OFF_M9);
    __hip_bfloat16* HW1b = (__hip_bfloat16*)(ws + OFF_HW1B);
    __hip_bfloat16* h1b  = (__hip_bfloat16*)(ws + OFF_H1B);
    float* agg2 = (float*)(ws + OFF_AGG2);
    float* P    = (float*)(ws + OFF_P);
    int* esrc   = (int*)(ws + OFF_ESRC);
    int* rowptr = (int*)(ws + OFF_RP);
    int* cursor = (int*)(ws + OFF_CUR);
    float* out  = (float*)d_out;

    hipMemsetAsync(cursor, 0, (size_t)kN * 4, stream);

    hist_kernel<<<dim3(1954), dim3(256), 0, stream>>>(dst, cursor);
    scan_kernel<<<dim3(1), dim3(256), 0, stream>>>(cursor, rowptr);
    fill_kernel<<<dim3(1954), dim3(256), 0, stream>>>(src, dst, cursor, esrc);

    prep_kernel<<<dim3(393), dim3(128), 0, stream>>>(Wp_a, Wp_m, Wp_t, W1,
        Wh_a, Wh_m, Wh_t, Wc_a, Wc_m, Wc_t, WpW1, M9);

    hw1_kernel<<<dim3(kHW1Blocks), dim3(256), 0, stream>>>(h_a, h_m, h_t, WpW1, HW1b);
    aggv_kernel<true><<<dim3(kN), dim3(64), 0, stream>>>(HW1b, rowptr, esrc, b1, h1b);
    aggv_kernel<false><<<dim3(kN), dim3(64), 0, stream>>>(h1b, rowptr, esrc, b1, agg2);
    gemm2_norm_p_kernel<<<dim3(kG2Blocks), dim3(256), 0, stream>>>(agg2, W2, b2, M9, P, out);
    cls_lite_kernel<<<dim3(2346), dim3(256), 0, stream>>>(P,
        (const int*)d_in[21], (const int*)d_in[22], (const int*)d_in[23],
        (const int*)d_in[24], (const int*)d_in[25], (const int*)d_in[26],
        (const int*)d_in[27], (const int*)d_in[28], (const int*)d_in[29],
        Wo_a, Wo_m, Wo_t, out, 782);
}